// Round 5
// baseline (277.580 us; speedup 1.0000x reference)
//
#include <hip/hip_runtime.h>
#include <hip/hip_bf16.h>

// MultiBertAttention fp32 I/O, bf16 MFMA internals.
// R5: (1) attn register-prefetch K/V staging (hide global latency behind compute),
//     (2) exp2 with log2e folded into Q projection scale,
//     (3) QKV + V^T GEMMs fused into one 768-block dispatch (3 blocks/CU),
//     (4) out-proj 64x128 tiles (512 blocks), prep (convert+transpose) fused.

typedef unsigned short u16;

#define D_MODEL 1024
#define NHEAD 16
#define HDIM 64
#define BATCH 2
#define SEQ 2048
#define MTOT (BATCH * SEQ)  // 4096

#define QSCALE 0.18033688011112042f  // (1/8) * log2(e)

using frag_ab = __attribute__((ext_vector_type(8))) short;  // 8 bf16 = 4 VGPRs
using frag_cd = __attribute__((ext_vector_type(4))) float;  // 4 fp32

__device__ __forceinline__ u16 f2u(float f) {  // RNE fp32->bf16
    union { float f; unsigned int i; } x;
    x.f = f;
    unsigned int r = x.i + 0x7fffu + ((x.i >> 16) & 1u);
    return (u16)(r >> 16);
}
__device__ __forceinline__ u16 f2u_fast(float f) {  // round-nearest-ties-away, 2 ops
    union { float f; unsigned int i; } x;
    x.f = f;
    return (u16)((x.i + 0x8000u) >> 16);
}

// ---------------------------------------------------------------------------
// prep: z<4 -> Wt[z][n][k] = bf16(W_z[k][n]) (32x32 LDS transpose);
//       z==4 -> xb = bf16(x), 16 elems/thread.
// grid (32,32,5), block (32,8).
// ---------------------------------------------------------------------------
__global__ void prep(const float* __restrict__ W0, const float* __restrict__ W1,
                     const float* __restrict__ W2, const float* __restrict__ W3,
                     const float* __restrict__ X, u16* __restrict__ Wt,
                     u16* __restrict__ Xb) {
    const int z = blockIdx.z;
    const int tx = threadIdx.x, ty = threadIdx.y;
    if (z < 4) {
        __shared__ u16 t[32][33];
        const float* W = (z == 0) ? W0 : (z == 1) ? W1 : (z == 2) ? W2 : W3;
        u16* o = Wt + (size_t)z * D_MODEL * D_MODEL;
        int n0 = blockIdx.x * 32, k0 = blockIdx.y * 32;
        #pragma unroll
        for (int i = ty; i < 32; i += 8) t[i][tx] = f2u(W[(size_t)(k0 + i) * D_MODEL + n0 + tx]);
        __syncthreads();
        #pragma unroll
        for (int i = ty; i < 32; i += 8) o[(size_t)(n0 + i) * D_MODEL + k0 + tx] = t[tx][i];
    } else {
        int tid = ty * 32 + tx;
        size_t base = ((size_t)(blockIdx.y * 32 + blockIdx.x) * 256 + tid) * 16;
        #pragma unroll
        for (int c = 0; c < 4; ++c) {
            float4 v = *(const float4*)&X[base + c * 4];
            ushort4 o;
            o.x = f2u(v.x); o.y = f2u(v.y); o.z = f2u(v.z); o.w = f2u(v.w);
            *(ushort4*)&Xb[base + c * 4] = o;
        }
    }
}

// ---------------------------------------------------------------------------
// Fused QKV + V^T GEMM, 768 blocks (1D):
//   bid < 512 : Q/K. z = bid>>8, tile t = bid&255 (8 n x 32 m).
//               C[m=s][n=dout] = xb . Wt[z]^T + b, scatter -> [B,H,S,Hd] bf16.
//               z==0 scaled by QSCALE (1/8 * log2e, for exp2 softmax).
//   bid >= 512: V^T. tile t (32 n x 8 m). C[m=dout][n=s] = WvT . xb^T + bv[m],
//               scatter -> [B,H,Hd,S] bf16.
// 128x128 tile, 4 waves x (64x64), BK=64, global_load_lds width-16.
// ---------------------------------------------------------------------------
__launch_bounds__(256, 2)
__global__ void gemm_qkvt(const u16* __restrict__ xb, const u16* __restrict__ Wt,
                          const float* __restrict__ bq, const float* __restrict__ bk,
                          const float* __restrict__ bv, u16* __restrict__ QKw,
                          u16* __restrict__ Vtw) {
    constexpr int BK = 64;
    __shared__ __attribute__((aligned(16))) u16 As[128 * BK];
    __shared__ __attribute__((aligned(16))) u16 Bs[128 * BK];

    const int tid = threadIdx.x;
    const int w = tid >> 6;
    const int lane = tid & 63;
    const int lrow = lane & 15, lquad = lane >> 4;
    const size_t WSZ = (size_t)D_MODEL * D_MODEL;

    const int bid = blockIdx.x;
    const bool vt = bid >= 512;
    const int z = vt ? 2 : (bid >> 8);
    const int t = vt ? (bid - 512) : (bid & 255);
    const int n0 = vt ? (t & 31) * 128 : (t & 7) * 128;
    const int m0 = vt ? (t >> 5) * 128 : (t >> 3) * 128;
    const u16* Ap = vt ? (Wt + 2 * WSZ) : xb;
    const u16* Bp = vt ? xb : (Wt + (size_t)z * WSZ);
    const float* bias = vt ? bv : (z ? bk : bq);

    frag_cd acc[4][4];
    #pragma unroll
    for (int i = 0; i < 4; i++)
        #pragma unroll
        for (int j = 0; j < 4; j++) acc[i][j] = (frag_cd){0.f, 0.f, 0.f, 0.f};

    const int wm = (w >> 1) * 64, wn = (w & 1) * 64;

    for (int k0 = 0; k0 < D_MODEL; k0 += BK) {
        __syncthreads();
        #pragma unroll
        for (int it = 0; it < 4; ++it) {
            int c = it * 256 + tid;
            int r = c >> 3, c8 = c & 7;
            const u16* ga = Ap + (size_t)(m0 + r) * D_MODEL + k0 + c8 * 8;
            char* la = (char*)As + (it * 256 + w * 64) * 16;
            __builtin_amdgcn_global_load_lds((const __attribute__((address_space(1))) void*)ga,
                                             (__attribute__((address_space(3))) void*)la, 16, 0, 0);
            const u16* gb = Bp + (size_t)(n0 + r) * D_MODEL + k0 + c8 * 8;
            char* lb = (char*)Bs + (it * 256 + w * 64) * 16;
            __builtin_amdgcn_global_load_lds((const __attribute__((address_space(1))) void*)gb,
                                             (__attribute__((address_space(3))) void*)lb, 16, 0, 0);
        }
        __syncthreads();

        #pragma unroll
        for (int kc = 0; kc < 2; ++kc) {
            frag_ab av[4], bvv[4];
            #pragma unroll
            for (int i = 0; i < 4; i++)
                av[i] = *(const frag_ab*)&As[(wm + i * 16 + lrow) * BK + kc * 32 + lquad * 8];
            #pragma unroll
            for (int j = 0; j < 4; j++)
                bvv[j] = *(const frag_ab*)&Bs[(wn + j * 16 + lrow) * BK + kc * 32 + lquad * 8];
            #pragma unroll
            for (int i = 0; i < 4; i++)
                #pragma unroll
                for (int j = 0; j < 4; j++)
                    acc[i][j] = __builtin_amdgcn_mfma_f32_16x16x32_bf16(av[i], bvv[j], acc[i][j], 0, 0, 0);
        }
    }

    const float scale = (!vt && z == 0) ? QSCALE : 1.0f;
    #pragma unroll
    for (int j = 0; j < 4; j++) {
        int gn = n0 + wn + j * 16 + lrow;
        #pragma unroll
        for (int i = 0; i < 4; i++) {
            #pragma unroll
            for (int rr = 0; rr < 4; ++rr) {
                int gm = m0 + wm + i * 16 + lquad * 4 + rr;
                if (!vt) {
                    float v = (acc[i][j][rr] + bias[gn]) * scale;
                    u16* oz = QKw + (size_t)z * ((size_t)MTOT * D_MODEL);
                    int b = gm >> 11, s = gm & (SEQ - 1);
                    int h = gn >> 6, d = gn & (HDIM - 1);
                    oz[(((size_t)(b * NHEAD + h)) * SEQ + s) * HDIM + d] = f2u(v);
                } else {
                    float v = acc[i][j][rr] + bias[gm];
                    int h = gm >> 6, d = gm & (HDIM - 1);
                    int b = gn >> 11, s = gn & (SEQ - 1);
                    Vtw[(((size_t)(b * NHEAD + h)) * HDIM + d) * SEQ + s] = f2u(v);
                }
            }
        }
    }
}

// ---------------------------------------------------------------------------
// Out projection: C[m][n] = A[m][:1024].Wo^T[n][:1024] + bo[n], fp32 store [M][N].
// 64x128 tile (512 blocks = 2/CU), 4 waves as 2x2 -> wave tile 32x64, acc[2][4].
// ---------------------------------------------------------------------------
__launch_bounds__(256, 2)
__global__ void gemm_out(const u16* __restrict__ A, const u16* __restrict__ Wt,
                         const float* __restrict__ bias, float* __restrict__ out) {
    constexpr int BK = 64;
    __shared__ __attribute__((aligned(16))) u16 As[64 * BK];
    __shared__ __attribute__((aligned(16))) u16 Bs[128 * BK];

    const int tid = threadIdx.x;
    const int w = tid >> 6;
    const int lane = tid & 63;
    const int lrow = lane & 15, lquad = lane >> 4;
    const int m0 = blockIdx.y * 64, n0 = blockIdx.x * 128;

    frag_cd acc[2][4];
    #pragma unroll
    for (int i = 0; i < 2; i++)
        #pragma unroll
        for (int j = 0; j < 4; j++) acc[i][j] = (frag_cd){0.f, 0.f, 0.f, 0.f};

    const int wm = (w >> 1) * 32, wn = (w & 1) * 64;

    for (int k0 = 0; k0 < D_MODEL; k0 += BK) {
        __syncthreads();
        #pragma unroll
        for (int it = 0; it < 2; ++it) {
            int c = it * 256 + tid;
            int r = c >> 3, c8 = c & 7;
            const u16* ga = A + (size_t)(m0 + r) * D_MODEL + k0 + c8 * 8;
            char* la = (char*)As + (it * 256 + w * 64) * 16;
            __builtin_amdgcn_global_load_lds((const __attribute__((address_space(1))) void*)ga,
                                             (__attribute__((address_space(3))) void*)la, 16, 0, 0);
        }
        #pragma unroll
        for (int it = 0; it < 4; ++it) {
            int c = it * 256 + tid;
            int r = c >> 3, c8 = c & 7;
            const u16* gb = Wt + (size_t)(n0 + r) * D_MODEL + k0 + c8 * 8;
            char* lb = (char*)Bs + (it * 256 + w * 64) * 16;
            __builtin_amdgcn_global_load_lds((const __attribute__((address_space(1))) void*)gb,
                                             (__attribute__((address_space(3))) void*)lb, 16, 0, 0);
        }
        __syncthreads();

        #pragma unroll
        for (int kc = 0; kc < 2; ++kc) {
            frag_ab av[2], bvv[4];
            #pragma unroll
            for (int i = 0; i < 2; i++)
                av[i] = *(const frag_ab*)&As[(wm + i * 16 + lrow) * BK + kc * 32 + lquad * 8];
            #pragma unroll
            for (int j = 0; j < 4; j++)
                bvv[j] = *(const frag_ab*)&Bs[(wn + j * 16 + lrow) * BK + kc * 32 + lquad * 8];
            #pragma unroll
            for (int i = 0; i < 2; i++)
                #pragma unroll
                for (int j = 0; j < 4; j++)
                    acc[i][j] = __builtin_amdgcn_mfma_f32_16x16x32_bf16(av[i], bvv[j], acc[i][j], 0, 0, 0);
        }
    }

    #pragma unroll
    for (int j = 0; j < 4; j++) {
        int gn = n0 + wn + j * 16 + lrow;
        float bvf = bias[gn];
        #pragma unroll
        for (int i = 0; i < 2; i++)
            #pragma unroll
            for (int rr = 0; rr < 4; ++rr) {
                int gm = m0 + wm + i * 16 + lquad * 4 + rr;
                out[(size_t)gm * D_MODEL + gn] = acc[i][j][rr] + bvf;
            }
    }
}

// ---------------------------------------------------------------------------
// Attention, exp2 softmax (Q pre-scaled by log2e/8). Grid (16, 32), block 256.
// Register-prefetch: tile kt+1 global loads issue right after the compute
// barrier, so QK/exp/PV compute hides the L2 latency; vmcnt wait lands at the
// next iteration's reg->LDS write.
// ---------------------------------------------------------------------------
__launch_bounds__(256, 2)
__global__ void attn_kernel(const u16* __restrict__ Q, const u16* __restrict__ K,
                            const u16* __restrict__ Vt, u16* __restrict__ O) {
    constexpr int SK = 72;
    __shared__ __attribute__((aligned(16))) u16 Ks[64 * SK];
    __shared__ __attribute__((aligned(16))) u16 Vs[64 * SK];
    __shared__ __attribute__((aligned(16))) u16 Ps[4 * 32 * SK];

    const int tid = threadIdx.x;
    const int w = tid >> 6;
    const int lane = tid & 63;
    const int lrow = lane & 15, lquad = lane >> 4;
    const int bh = blockIdx.y;
    const int q0 = blockIdx.x * 128;
    const size_t base = (size_t)bh * SEQ * HDIM;
    const u16* Qg = Q + base;
    const u16* Kg = K + base;
    const u16* Vg = Vt + base;  // [d][s]

    // staging coords (shared by load & write)
    const int sr = tid >> 3, sc8 = (tid & 7) * 8;  // +256 -> +32 rows

    frag_ab qf[2][2];
    #pragma unroll
    for (int sub = 0; sub < 2; ++sub)
        #pragma unroll
        for (int kc = 0; kc < 2; ++kc)
            qf[sub][kc] = *(const frag_ab*)&Qg[(size_t)(q0 + w * 32 + sub * 16 + lrow) * HDIM + kc * 32 + lquad * 8];

    frag_cd accO[2][4], lacc[2];
    #pragma unroll
    for (int sub = 0; sub < 2; ++sub) {
        lacc[sub] = (frag_cd){0.f, 0.f, 0.f, 0.f};
        #pragma unroll
        for (int df = 0; df < 4; df++) accO[sub][df] = (frag_cd){0.f, 0.f, 0.f, 0.f};
    }
    frag_ab ones;
    #pragma unroll
    for (int t = 0; t < 8; ++t) ones[t] = (short)0x3F80;  // bf16 1.0

    u16* Pw = Ps + w * 32 * SK;

    // prologue: prefetch tile 0 into registers
    uint4 kreg[2], vreg[2];
    #pragma unroll
    for (int it = 0; it < 2; ++it) {
        int r = sr + it * 32;
        kreg[it] = *(const uint4*)&Kg[(size_t)r * HDIM + sc8];
        vreg[it] = *(const uint4*)&Vg[(size_t)r * SEQ + sc8];
    }

    for (int kt = 0; kt < SEQ / 64; ++kt) {
        __syncthreads();  // previous iteration's readers done
        #pragma unroll
        for (int it = 0; it < 2; ++it) {
            int r = sr + it * 32;
            *(uint4*)&Ks[r * SK + sc8] = kreg[it];
            *(uint4*)&Vs[r * SK + sc8] = vreg[it];
        }
        __syncthreads();  // writes visible

        // issue next tile's global loads now; compute below hides the latency
        {
            int ktn = (kt + 1 < SEQ / 64) ? kt + 1 : kt;
            #pragma unroll
            for (int it = 0; it < 2; ++it) {
                int r = sr + it * 32;
                kreg[it] = *(const uint4*)&Kg[(size_t)(ktn * 64 + r) * HDIM + sc8];
                vreg[it] = *(const uint4*)&Vg[(size_t)r * SEQ + ktn * 64 + sc8];
            }
        }

        frag_cd sc[2][4];
        #pragma unroll
        for (int sub = 0; sub < 2; ++sub)
            #pragma unroll
            for (int nf = 0; nf < 4; nf++) sc[sub][nf] = (frag_cd){0.f, 0.f, 0.f, 0.f};
        #pragma unroll
        for (int kc = 0; kc < 2; ++kc) {
            #pragma unroll
            for (int nf = 0; nf < 4; nf++) {
                frag_ab kf = *(const frag_ab*)&Ks[(nf * 16 + lrow) * SK + kc * 32 + lquad * 8];
                #pragma unroll
                for (int sub = 0; sub < 2; ++sub)
                    sc[sub][nf] = __builtin_amdgcn_mfma_f32_16x16x32_bf16(qf[sub][kc], kf, sc[sub][nf], 0, 0, 0);
            }
        }

        // p = 2^s (Q pre-scaled by log2e/8) -> Pw[q][key] (C-layout scatter)
        #pragma unroll
        for (int sub = 0; sub < 2; ++sub)
            #pragma unroll
            for (int nf = 0; nf < 4; nf++)
                #pragma unroll
                for (int i = 0; i < 4; i++)
                    Pw[(sub * 16 + lquad * 4 + i) * SK + nf * 16 + lrow] = f2u_fast(exp2f(sc[sub][nf][i]));

        #pragma unroll
        for (int kc = 0; kc < 2; ++kc) {
            frag_ab pf[2];
            #pragma unroll
            for (int sub = 0; sub < 2; ++sub)
                pf[sub] = *(const frag_ab*)&Pw[(sub * 16 + lrow) * SK + kc * 32 + lquad * 8];
            #pragma unroll
            for (int sub = 0; sub < 2; ++sub)
                lacc[sub] = __builtin_amdgcn_mfma_f32_16x16x32_bf16(pf[sub], ones, lacc[sub], 0, 0, 0);
            #pragma unroll
            for (int df = 0; df < 4; df++) {
                frag_ab vf = *(const frag_ab*)&Vs[(df * 16 + lrow) * SK + kc * 32 + lquad * 8];
                #pragma unroll
                for (int sub = 0; sub < 2; ++sub)
                    accO[sub][df] = __builtin_amdgcn_mfma_f32_16x16x32_bf16(pf[sub], vf, accO[sub][df], 0, 0, 0);
            }
        }
    }

    const int b = bh >> 4, h = bh & (NHEAD - 1);
    #pragma unroll
    for (int sub = 0; sub < 2; ++sub)
        #pragma unroll
        for (int df = 0; df < 4; df++)
            #pragma unroll
            for (int i = 0; i < 4; i++) {
                int s = q0 + w * 32 + sub * 16 + lquad * 4 + i;
                int d = df * 16 + lrow;
                O[((size_t)(b * SEQ + s)) * D_MODEL + h * HDIM + d] = f2u(accO[sub][df][i] / lacc[sub][i]);
            }
}

// ---------------------------------------------------------------------------
// Workspace (u16 elems): xb [0,4M) | Wt 4 slabs [4M,8M) | Q,K [8M,16M)
//                        Vt [16M,20M) | attn-out [20M,24M)   = 48 MB
// ---------------------------------------------------------------------------
extern "C" void kernel_launch(void* const* d_in, const int* in_sizes, int n_in,
                              void* d_out, int out_size, void* d_ws, size_t ws_size,
                              hipStream_t stream) {
    const float* x  = (const float*)d_in[0];
    const float* Wq = (const float*)d_in[1];
    const float* bq = (const float*)d_in[2];
    const float* Wk = (const float*)d_in[3];
    const float* bk = (const float*)d_in[4];
    const float* Wv = (const float*)d_in[5];
    const float* bv = (const float*)d_in[6];
    const float* Wo = (const float*)d_in[7];
    const float* bo = (const float*)d_in[8];

    u16* ws = (u16*)d_ws;
    const size_t WSZ = (size_t)D_MODEL * D_MODEL;    // 1M elems
    const size_t TSZ = (size_t)MTOT * D_MODEL;       // 4M elems
    u16* xb  = ws;
    u16* Wt  = ws + 4 * WSZ;
    u16* QKw = ws + 8 * WSZ;        // Q slab 0, K slab 1
    u16* Vtw = QKw + 2 * TSZ;
    u16* Aw  = Vtw + TSZ;

    prep<<<dim3(32, 32, 5), dim3(32, 8), 0, stream>>>(Wq, Wk, Wv, Wo, x, Wt, xb);
    gemm_qkvt<<<dim3(768), 256, 0, stream>>>(xb, Wt, bq, bk, bv, QKw, Vtw);
    attn_kernel<<<dim3(16, 32), 256, 0, stream>>>(QKw, QKw + TSZ, Vtw, Aw);
    gemm_out<<<dim3(8, 64), 256, 0, stream>>>(Aw, Wt + 3 * WSZ, bo, (float*)d_out);
}

// Round 6
// 223.631 us; speedup vs baseline: 1.2412x; 1.2412x over previous
//
#include <hip/hip_runtime.h>
#include <hip/hip_bf16.h>

// MultiBertAttention fp32 I/O, bf16 MFMA internals.
// R6: revert R5's attn register-prefetch (regressed: spill-class HBM writes 3x).
//     Keep R4 synchronous staging + exp2(QSCALE); NEW: 128-key chunks per barrier
//     (16 barrier-pairs instead of 32). Keep R5's fused prep/gemm_qkvt/gemm_out.

typedef unsigned short u16;

#define D_MODEL 1024
#define NHEAD 16
#define HDIM 64
#define BATCH 2
#define SEQ 2048
#define MTOT (BATCH * SEQ)  // 4096

#define QSCALE 0.18033688011112042f  // (1/8) * log2(e)

using frag_ab = __attribute__((ext_vector_type(8))) short;  // 8 bf16 = 4 VGPRs
using frag_cd = __attribute__((ext_vector_type(4))) float;  // 4 fp32

__device__ __forceinline__ u16 f2u(float f) {  // RNE fp32->bf16
    union { float f; unsigned int i; } x;
    x.f = f;
    unsigned int r = x.i + 0x7fffu + ((x.i >> 16) & 1u);
    return (u16)(r >> 16);
}
__device__ __forceinline__ u16 f2u_fast(float f) {  // round-nearest-ties-away, 2 ops
    union { float f; unsigned int i; } x;
    x.f = f;
    return (u16)((x.i + 0x8000u) >> 16);
}

// ---------------------------------------------------------------------------
// prep: z<4 -> Wt[z][n][k] = bf16(W_z[k][n]); z==4 -> xb = bf16(x).
// ---------------------------------------------------------------------------
__global__ void prep(const float* __restrict__ W0, const float* __restrict__ W1,
                     const float* __restrict__ W2, const float* __restrict__ W3,
                     const float* __restrict__ X, u16* __restrict__ Wt,
                     u16* __restrict__ Xb) {
    const int z = blockIdx.z;
    const int tx = threadIdx.x, ty = threadIdx.y;
    if (z < 4) {
        __shared__ u16 t[32][33];
        const float* W = (z == 0) ? W0 : (z == 1) ? W1 : (z == 2) ? W2 : W3;
        u16* o = Wt + (size_t)z * D_MODEL * D_MODEL;
        int n0 = blockIdx.x * 32, k0 = blockIdx.y * 32;
        #pragma unroll
        for (int i = ty; i < 32; i += 8) t[i][tx] = f2u(W[(size_t)(k0 + i) * D_MODEL + n0 + tx]);
        __syncthreads();
        #pragma unroll
        for (int i = ty; i < 32; i += 8) o[(size_t)(n0 + i) * D_MODEL + k0 + tx] = t[tx][i];
    } else {
        int tid = ty * 32 + tx;
        size_t base = ((size_t)(blockIdx.y * 32 + blockIdx.x) * 256 + tid) * 16;
        #pragma unroll
        for (int c = 0; c < 4; ++c) {
            float4 v = *(const float4*)&X[base + c * 4];
            ushort4 o;
            o.x = f2u(v.x); o.y = f2u(v.y); o.z = f2u(v.z); o.w = f2u(v.w);
            *(ushort4*)&Xb[base + c * 4] = o;
        }
    }
}

// ---------------------------------------------------------------------------
// Fused QKV + V^T GEMM, 768 blocks (1D). 128x128 tile, BK=64, global_load_lds.
// ---------------------------------------------------------------------------
__launch_bounds__(256, 2)
__global__ void gemm_qkvt(const u16* __restrict__ xb, const u16* __restrict__ Wt,
                          const float* __restrict__ bq, const float* __restrict__ bk,
                          const float* __restrict__ bv, u16* __restrict__ QKw,
                          u16* __restrict__ Vtw) {
    constexpr int BK = 64;
    __shared__ __attribute__((aligned(16))) u16 As[128 * BK];
    __shared__ __attribute__((aligned(16))) u16 Bs[128 * BK];

    const int tid = threadIdx.x;
    const int w = tid >> 6;
    const int lane = tid & 63;
    const int lrow = lane & 15, lquad = lane >> 4;
    const size_t WSZ = (size_t)D_MODEL * D_MODEL;

    const int bid = blockIdx.x;
    const bool vt = bid >= 512;
    const int z = vt ? 2 : (bid >> 8);
    const int t = vt ? (bid - 512) : (bid & 255);
    const int n0 = vt ? (t & 31) * 128 : (t & 7) * 128;
    const int m0 = vt ? (t >> 5) * 128 : (t >> 3) * 128;
    const u16* Ap = vt ? (Wt + 2 * WSZ) : xb;
    const u16* Bp = vt ? xb : (Wt + (size_t)z * WSZ);
    const float* bias = vt ? bv : (z ? bk : bq);

    frag_cd acc[4][4];
    #pragma unroll
    for (int i = 0; i < 4; i++)
        #pragma unroll
        for (int j = 0; j < 4; j++) acc[i][j] = (frag_cd){0.f, 0.f, 0.f, 0.f};

    const int wm = (w >> 1) * 64, wn = (w & 1) * 64;

    for (int k0 = 0; k0 < D_MODEL; k0 += BK) {
        __syncthreads();
        #pragma unroll
        for (int it = 0; it < 4; ++it) {
            int c = it * 256 + tid;
            int r = c >> 3, c8 = c & 7;
            const u16* ga = Ap + (size_t)(m0 + r) * D_MODEL + k0 + c8 * 8;
            char* la = (char*)As + (it * 256 + w * 64) * 16;
            __builtin_amdgcn_global_load_lds((const __attribute__((address_space(1))) void*)ga,
                                             (__attribute__((address_space(3))) void*)la, 16, 0, 0);
            const u16* gb = Bp + (size_t)(n0 + r) * D_MODEL + k0 + c8 * 8;
            char* lb = (char*)Bs + (it * 256 + w * 64) * 16;
            __builtin_amdgcn_global_load_lds((const __attribute__((address_space(1))) void*)gb,
                                             (__attribute__((address_space(3))) void*)lb, 16, 0, 0);
        }
        __syncthreads();

        #pragma unroll
        for (int kc = 0; kc < 2; ++kc) {
            frag_ab av[4], bvv[4];
            #pragma unroll
            for (int i = 0; i < 4; i++)
                av[i] = *(const frag_ab*)&As[(wm + i * 16 + lrow) * BK + kc * 32 + lquad * 8];
            #pragma unroll
            for (int j = 0; j < 4; j++)
                bvv[j] = *(const frag_ab*)&Bs[(wn + j * 16 + lrow) * BK + kc * 32 + lquad * 8];
            #pragma unroll
            for (int i = 0; i < 4; i++)
                #pragma unroll
                for (int j = 0; j < 4; j++)
                    acc[i][j] = __builtin_amdgcn_mfma_f32_16x16x32_bf16(av[i], bvv[j], acc[i][j], 0, 0, 0);
        }
    }

    const float scale = (!vt && z == 0) ? QSCALE : 1.0f;
    #pragma unroll
    for (int j = 0; j < 4; j++) {
        int gn = n0 + wn + j * 16 + lrow;
        #pragma unroll
        for (int i = 0; i < 4; i++) {
            #pragma unroll
            for (int rr = 0; rr < 4; ++rr) {
                int gm = m0 + wm + i * 16 + lquad * 4 + rr;
                if (!vt) {
                    float v = (acc[i][j][rr] + bias[gn]) * scale;
                    u16* oz = QKw + (size_t)z * ((size_t)MTOT * D_MODEL);
                    int b = gm >> 11, s = gm & (SEQ - 1);
                    int h = gn >> 6, d = gn & (HDIM - 1);
                    oz[(((size_t)(b * NHEAD + h)) * SEQ + s) * HDIM + d] = f2u(v);
                } else {
                    float v = acc[i][j][rr] + bias[gm];
                    int h = gm >> 6, d = gm & (HDIM - 1);
                    int b = gn >> 11, s = gn & (SEQ - 1);
                    Vtw[(((size_t)(b * NHEAD + h)) * HDIM + d) * SEQ + s] = f2u(v);
                }
            }
        }
    }
}

// ---------------------------------------------------------------------------
// Out projection: 64x128 tile (512 blocks), fp32 store.
// ---------------------------------------------------------------------------
__launch_bounds__(256, 2)
__global__ void gemm_out(const u16* __restrict__ A, const u16* __restrict__ Wt,
                         const float* __restrict__ bias, float* __restrict__ out) {
    constexpr int BK = 64;
    __shared__ __attribute__((aligned(16))) u16 As[64 * BK];
    __shared__ __attribute__((aligned(16))) u16 Bs[128 * BK];

    const int tid = threadIdx.x;
    const int w = tid >> 6;
    const int lane = tid & 63;
    const int lrow = lane & 15, lquad = lane >> 4;
    const int m0 = blockIdx.y * 64, n0 = blockIdx.x * 128;

    frag_cd acc[2][4];
    #pragma unroll
    for (int i = 0; i < 2; i++)
        #pragma unroll
        for (int j = 0; j < 4; j++) acc[i][j] = (frag_cd){0.f, 0.f, 0.f, 0.f};

    const int wm = (w >> 1) * 32, wn = (w & 1) * 64;

    for (int k0 = 0; k0 < D_MODEL; k0 += BK) {
        __syncthreads();
        #pragma unroll
        for (int it = 0; it < 2; ++it) {
            int c = it * 256 + tid;
            int r = c >> 3, c8 = c & 7;
            const u16* ga = A + (size_t)(m0 + r) * D_MODEL + k0 + c8 * 8;
            char* la = (char*)As + (it * 256 + w * 64) * 16;
            __builtin_amdgcn_global_load_lds((const __attribute__((address_space(1))) void*)ga,
                                             (__attribute__((address_space(3))) void*)la, 16, 0, 0);
        }
        #pragma unroll
        for (int it = 0; it < 4; ++it) {
            int c = it * 256 + tid;
            int r = c >> 3, c8 = c & 7;
            const u16* gb = Wt + (size_t)(n0 + r) * D_MODEL + k0 + c8 * 8;
            char* lb = (char*)Bs + (it * 256 + w * 64) * 16;
            __builtin_amdgcn_global_load_lds((const __attribute__((address_space(1))) void*)gb,
                                             (__attribute__((address_space(3))) void*)lb, 16, 0, 0);
        }
        __syncthreads();

        #pragma unroll
        for (int kc = 0; kc < 2; ++kc) {
            frag_ab av[2], bvv[4];
            #pragma unroll
            for (int i = 0; i < 2; i++)
                av[i] = *(const frag_ab*)&As[(wm + i * 16 + lrow) * BK + kc * 32 + lquad * 8];
            #pragma unroll
            for (int j = 0; j < 4; j++)
                bvv[j] = *(const frag_ab*)&Bs[(wn + j * 16 + lrow) * BK + kc * 32 + lquad * 8];
            #pragma unroll
            for (int i = 0; i < 2; i++)
                #pragma unroll
                for (int j = 0; j < 4; j++)
                    acc[i][j] = __builtin_amdgcn_mfma_f32_16x16x32_bf16(av[i], bvv[j], acc[i][j], 0, 0, 0);
        }
    }

    #pragma unroll
    for (int j = 0; j < 4; j++) {
        int gn = n0 + wn + j * 16 + lrow;
        float bvf = bias[gn];
        #pragma unroll
        for (int i = 0; i < 2; i++)
            #pragma unroll
            for (int rr = 0; rr < 4; ++rr) {
                int gm = m0 + wm + i * 16 + lquad * 4 + rr;
                out[(size_t)gm * D_MODEL + gn] = acc[i][j][rr] + bvf;
            }
    }
}

// ---------------------------------------------------------------------------
// Attention, exp2 softmax, 128-key chunks (16 barrier-pairs per slab).
// Grid (16, 32), block 256 (4 waves x 32 q rows). R4-style synchronous staging.
// LDS: Ks[128][72] + Vs[64][136] + Ps[4][32][136] = 70.7 KB -> 2 blocks/CU.
// ---------------------------------------------------------------------------
__launch_bounds__(256, 2)
__global__ void attn_kernel(const u16* __restrict__ Q, const u16* __restrict__ K,
                            const u16* __restrict__ Vt, u16* __restrict__ O) {
    constexpr int SKK = 72;   // K row stride (64 d + pad)
    constexpr int SKV = 136;  // V/P row stride (128 keys + pad)
    __shared__ __attribute__((aligned(16))) u16 Ks[128 * SKK];
    __shared__ __attribute__((aligned(16))) u16 Vs[64 * SKV];
    __shared__ __attribute__((aligned(16))) u16 Ps[4 * 32 * SKV];

    const int tid = threadIdx.x;
    const int w = tid >> 6;
    const int lane = tid & 63;
    const int lrow = lane & 15, lquad = lane >> 4;
    const int bh = blockIdx.y;
    const int q0 = blockIdx.x * 128;
    const size_t base = (size_t)bh * SEQ * HDIM;
    const u16* Qg = Q + base;
    const u16* Kg = K + base;
    const u16* Vg = Vt + base;  // [d][s]

    frag_ab qf[2][2];
    #pragma unroll
    for (int sub = 0; sub < 2; ++sub)
        #pragma unroll
        for (int kc = 0; kc < 2; ++kc)
            qf[sub][kc] = *(const frag_ab*)&Qg[(size_t)(q0 + w * 32 + sub * 16 + lrow) * HDIM + kc * 32 + lquad * 8];

    frag_cd accO[2][4], lacc[2];
    #pragma unroll
    for (int sub = 0; sub < 2; ++sub) {
        lacc[sub] = (frag_cd){0.f, 0.f, 0.f, 0.f};
        #pragma unroll
        for (int df = 0; df < 4; df++) accO[sub][df] = (frag_cd){0.f, 0.f, 0.f, 0.f};
    }
    frag_ab ones;
    #pragma unroll
    for (int t = 0; t < 8; ++t) ones[t] = (short)0x3F80;  // bf16 1.0

    u16* Pw = Ps + w * 32 * SKV;

    for (int kt = 0; kt < SEQ / 128; ++kt) {
        __syncthreads();
        #pragma unroll
        for (int it = 0; it < 4; ++it) {
            int c = it * 256 + tid;
            int rk = c >> 3, ck = (c & 7) * 8;
            *(uint4*)&Ks[rk * SKK + ck] = *(const uint4*)&Kg[(size_t)(kt * 128 + rk) * HDIM + ck];
            int rv = c >> 4, cv = (c & 15) * 8;
            *(uint4*)&Vs[rv * SKV + cv] = *(const uint4*)&Vg[(size_t)rv * SEQ + kt * 128 + cv];
        }
        __syncthreads();

        // scores: 32q x 128key per wave
        frag_cd sc[2][8];
        #pragma unroll
        for (int sub = 0; sub < 2; ++sub)
            #pragma unroll
            for (int nf = 0; nf < 8; nf++) sc[sub][nf] = (frag_cd){0.f, 0.f, 0.f, 0.f};
        #pragma unroll
        for (int kc = 0; kc < 2; ++kc) {
            #pragma unroll
            for (int nf = 0; nf < 8; nf++) {
                frag_ab kf = *(const frag_ab*)&Ks[(nf * 16 + lrow) * SKK + kc * 32 + lquad * 8];
                #pragma unroll
                for (int sub = 0; sub < 2; ++sub)
                    sc[sub][nf] = __builtin_amdgcn_mfma_f32_16x16x32_bf16(qf[sub][kc], kf, sc[sub][nf], 0, 0, 0);
            }
        }

        // p = 2^s -> Pw[q][key] (C-layout scatter)
        #pragma unroll
        for (int sub = 0; sub < 2; ++sub)
            #pragma unroll
            for (int nf = 0; nf < 8; nf++)
                #pragma unroll
                for (int i = 0; i < 4; i++)
                    Pw[(sub * 16 + lquad * 4 + i) * SKV + nf * 16 + lrow] = f2u_fast(exp2f(sc[sub][nf][i]));

        // PV + rowsum over 128 keys
        #pragma unroll
        for (int kc = 0; kc < 4; ++kc) {
            frag_ab pf[2];
            #pragma unroll
            for (int sub = 0; sub < 2; ++sub)
                pf[sub] = *(const frag_ab*)&Pw[(sub * 16 + lrow) * SKV + kc * 32 + lquad * 8];
            #pragma unroll
            for (int sub = 0; sub < 2; ++sub)
                lacc[sub] = __builtin_amdgcn_mfma_f32_16x16x32_bf16(pf[sub], ones, lacc[sub], 0, 0, 0);
            #pragma unroll
            for (int df = 0; df < 4; df++) {
                frag_ab vf = *(const frag_ab*)&Vs[(df * 16 + lrow) * SKV + kc * 32 + lquad * 8];
                #pragma unroll
                for (int sub = 0; sub < 2; ++sub)
                    accO[sub][df] = __builtin_amdgcn_mfma_f32_16x16x32_bf16(pf[sub], vf, accO[sub][df], 0, 0, 0);
            }
        }
    }

    const int b = bh >> 4, h = bh & (NHEAD - 1);
    #pragma unroll
    for (int sub = 0; sub < 2; ++sub)
        #pragma unroll
        for (int df = 0; df < 4; df++)
            #pragma unroll
            for (int i = 0; i < 4; i++) {
                int s = q0 + w * 32 + sub * 16 + lquad * 4 + i;
                int d = df * 16 + lrow;
                O[((size_t)(b * SEQ + s)) * D_MODEL + h * HDIM + d] = f2u(accO[sub][df][i] / lacc[sub][i]);
            }
}

// ---------------------------------------------------------------------------
// Workspace (u16 elems): xb [0,4M) | Wt 4 slabs [4M,8M) | Q,K [8M,16M)
//                        Vt [16M,20M) | attn-out [20M,24M)   = 48 MB
// ---------------------------------------------------------------------------
extern "C" void kernel_launch(void* const* d_in, const int* in_sizes, int n_in,
                              void* d_out, int out_size, void* d_ws, size_t ws_size,
                              hipStream_t stream) {
    const float* x  = (const float*)d_in[0];
    const float* Wq = (const float*)d_in[1];
    const float* bq = (const float*)d_in[2];
    const float* Wk = (const float*)d_in[3];
    const float* bk = (const float*)d_in[4];
    const float* Wv = (const float*)d_in[5];
    const float* bv = (const float*)d_in[6];
    const float* Wo = (const float*)d_in[7];
    const float* bo = (const float*)d_in[8];

    u16* ws = (u16*)d_ws;
    const size_t WSZ = (size_t)D_MODEL * D_MODEL;    // 1M elems
    const size_t TSZ = (size_t)MTOT * D_MODEL;       // 4M elems
    u16* xb  = ws;
    u16* Wt  = ws + 4 * WSZ;
    u16* QKw = ws + 8 * WSZ;        // Q slab 0, K slab 1
    u16* Vtw = QKw + 2 * TSZ;
    u16* Aw  = Vtw + TSZ;

    prep<<<dim3(32, 32, 5), dim3(32, 8), 0, stream>>>(Wq, Wk, Wv, Wo, x, Wt, xb);
    gemm_qkvt<<<dim3(768), 256, 0, stream>>>(xb, Wt, bq, bk, bv, QKw, Vtw);
    attn_kernel<<<dim3(16, 32), 256, 0, stream>>>(QKw, QKw + TSZ, Vtw, Aw);
    gemm_out<<<dim3(8, 64), 256, 0, stream>>>(Aw, Wt + 3 * WSZ, bo, (float*)d_out);
}

// Round 7
// 223.126 us; speedup vs baseline: 1.2440x; 1.0023x over previous
//
#include <hip/hip_runtime.h>
#include <hip/hip_bf16.h>

// MultiBertAttention fp32 I/O, bf16 MFMA internals.
// R7: attn -> 512-thread blocks (8 waves x 16 q-rows, same 128-q tile, same LDS)
//     to lift waves/SIMD 2->4 (occupancy was the R6 limiter at 18%).
//     gemm_qkvt -> __launch_bounds__(256,3) for 3 blocks/CU (768 blocks = 1 pass).

typedef unsigned short u16;

#define D_MODEL 1024
#define NHEAD 16
#define HDIM 64
#define BATCH 2
#define SEQ 2048
#define MTOT (BATCH * SEQ)  // 4096

#define QSCALE 0.18033688011112042f  // (1/8) * log2(e)

using frag_ab = __attribute__((ext_vector_type(8))) short;  // 8 bf16 = 4 VGPRs
using frag_cd = __attribute__((ext_vector_type(4))) float;  // 4 fp32

__device__ __forceinline__ u16 f2u(float f) {  // RNE fp32->bf16
    union { float f; unsigned int i; } x;
    x.f = f;
    unsigned int r = x.i + 0x7fffu + ((x.i >> 16) & 1u);
    return (u16)(r >> 16);
}
__device__ __forceinline__ u16 f2u_fast(float f) {  // round-nearest-ties-away, 2 ops
    union { float f; unsigned int i; } x;
    x.f = f;
    return (u16)((x.i + 0x8000u) >> 16);
}

// ---------------------------------------------------------------------------
// prep: z<4 -> Wt[z][n][k] = bf16(W_z[k][n]); z==4 -> xb = bf16(x).
// ---------------------------------------------------------------------------
__global__ void prep(const float* __restrict__ W0, const float* __restrict__ W1,
                     const float* __restrict__ W2, const float* __restrict__ W3,
                     const float* __restrict__ X, u16* __restrict__ Wt,
                     u16* __restrict__ Xb) {
    const int z = blockIdx.z;
    const int tx = threadIdx.x, ty = threadIdx.y;
    if (z < 4) {
        __shared__ u16 t[32][33];
        const float* W = (z == 0) ? W0 : (z == 1) ? W1 : (z == 2) ? W2 : W3;
        u16* o = Wt + (size_t)z * D_MODEL * D_MODEL;
        int n0 = blockIdx.x * 32, k0 = blockIdx.y * 32;
        #pragma unroll
        for (int i = ty; i < 32; i += 8) t[i][tx] = f2u(W[(size_t)(k0 + i) * D_MODEL + n0 + tx]);
        __syncthreads();
        #pragma unroll
        for (int i = ty; i < 32; i += 8) o[(size_t)(n0 + i) * D_MODEL + k0 + tx] = t[tx][i];
    } else {
        int tid = ty * 32 + tx;
        size_t base = ((size_t)(blockIdx.y * 32 + blockIdx.x) * 256 + tid) * 16;
        #pragma unroll
        for (int c = 0; c < 4; ++c) {
            float4 v = *(const float4*)&X[base + c * 4];
            ushort4 o;
            o.x = f2u(v.x); o.y = f2u(v.y); o.z = f2u(v.z); o.w = f2u(v.w);
            *(ushort4*)&Xb[base + c * 4] = o;
        }
    }
}

// ---------------------------------------------------------------------------
// Fused QKV + V^T GEMM, 768 blocks (1D). 128x128 tile, BK=64, global_load_lds.
// launch_bounds (256,3): 3 blocks/CU -> 768 blocks in one resident pass.
// ---------------------------------------------------------------------------
__launch_bounds__(256, 3)
__global__ void gemm_qkvt(const u16* __restrict__ xb, const u16* __restrict__ Wt,
                          const float* __restrict__ bq, const float* __restrict__ bk,
                          const float* __restrict__ bv, u16* __restrict__ QKw,
                          u16* __restrict__ Vtw) {
    constexpr int BK = 64;
    __shared__ __attribute__((aligned(16))) u16 As[128 * BK];
    __shared__ __attribute__((aligned(16))) u16 Bs[128 * BK];

    const int tid = threadIdx.x;
    const int w = tid >> 6;
    const int lane = tid & 63;
    const int lrow = lane & 15, lquad = lane >> 4;
    const size_t WSZ = (size_t)D_MODEL * D_MODEL;

    const int bid = blockIdx.x;
    const bool vt = bid >= 512;
    const int z = vt ? 2 : (bid >> 8);
    const int t = vt ? (bid - 512) : (bid & 255);
    const int n0 = vt ? (t & 31) * 128 : (t & 7) * 128;
    const int m0 = vt ? (t >> 5) * 128 : (t >> 3) * 128;
    const u16* Ap = vt ? (Wt + 2 * WSZ) : xb;
    const u16* Bp = vt ? xb : (Wt + (size_t)z * WSZ);
    const float* bias = vt ? bv : (z ? bk : bq);

    frag_cd acc[4][4];
    #pragma unroll
    for (int i = 0; i < 4; i++)
        #pragma unroll
        for (int j = 0; j < 4; j++) acc[i][j] = (frag_cd){0.f, 0.f, 0.f, 0.f};

    const int wm = (w >> 1) * 64, wn = (w & 1) * 64;

    for (int k0 = 0; k0 < D_MODEL; k0 += BK) {
        __syncthreads();
        #pragma unroll
        for (int it = 0; it < 4; ++it) {
            int c = it * 256 + tid;
            int r = c >> 3, c8 = c & 7;
            const u16* ga = Ap + (size_t)(m0 + r) * D_MODEL + k0 + c8 * 8;
            char* la = (char*)As + (it * 256 + w * 64) * 16;
            __builtin_amdgcn_global_load_lds((const __attribute__((address_space(1))) void*)ga,
                                             (__attribute__((address_space(3))) void*)la, 16, 0, 0);
            const u16* gb = Bp + (size_t)(n0 + r) * D_MODEL + k0 + c8 * 8;
            char* lb = (char*)Bs + (it * 256 + w * 64) * 16;
            __builtin_amdgcn_global_load_lds((const __attribute__((address_space(1))) void*)gb,
                                             (__attribute__((address_space(3))) void*)lb, 16, 0, 0);
        }
        __syncthreads();

        #pragma unroll
        for (int kc = 0; kc < 2; ++kc) {
            frag_ab av[4], bvv[4];
            #pragma unroll
            for (int i = 0; i < 4; i++)
                av[i] = *(const frag_ab*)&As[(wm + i * 16 + lrow) * BK + kc * 32 + lquad * 8];
            #pragma unroll
            for (int j = 0; j < 4; j++)
                bvv[j] = *(const frag_ab*)&Bs[(wn + j * 16 + lrow) * BK + kc * 32 + lquad * 8];
            #pragma unroll
            for (int i = 0; i < 4; i++)
                #pragma unroll
                for (int j = 0; j < 4; j++)
                    acc[i][j] = __builtin_amdgcn_mfma_f32_16x16x32_bf16(av[i], bvv[j], acc[i][j], 0, 0, 0);
        }
    }

    const float scale = (!vt && z == 0) ? QSCALE : 1.0f;
    #pragma unroll
    for (int j = 0; j < 4; j++) {
        int gn = n0 + wn + j * 16 + lrow;
        #pragma unroll
        for (int i = 0; i < 4; i++) {
            #pragma unroll
            for (int rr = 0; rr < 4; ++rr) {
                int gm = m0 + wm + i * 16 + lquad * 4 + rr;
                if (!vt) {
                    float v = (acc[i][j][rr] + bias[gn]) * scale;
                    u16* oz = QKw + (size_t)z * ((size_t)MTOT * D_MODEL);
                    int b = gm >> 11, s = gm & (SEQ - 1);
                    int h = gn >> 6, d = gn & (HDIM - 1);
                    oz[(((size_t)(b * NHEAD + h)) * SEQ + s) * HDIM + d] = f2u(v);
                } else {
                    float v = acc[i][j][rr] + bias[gm];
                    int h = gm >> 6, d = gm & (HDIM - 1);
                    int b = gn >> 11, s = gn & (SEQ - 1);
                    Vtw[(((size_t)(b * NHEAD + h)) * HDIM + d) * SEQ + s] = f2u(v);
                }
            }
        }
    }
}

// ---------------------------------------------------------------------------
// Out projection: 64x128 tile (512 blocks), fp32 store.
// ---------------------------------------------------------------------------
__launch_bounds__(256, 2)
__global__ void gemm_out(const u16* __restrict__ A, const u16* __restrict__ Wt,
                         const float* __restrict__ bias, float* __restrict__ out) {
    constexpr int BK = 64;
    __shared__ __attribute__((aligned(16))) u16 As[64 * BK];
    __shared__ __attribute__((aligned(16))) u16 Bs[128 * BK];

    const int tid = threadIdx.x;
    const int w = tid >> 6;
    const int lane = tid & 63;
    const int lrow = lane & 15, lquad = lane >> 4;
    const int m0 = blockIdx.y * 64, n0 = blockIdx.x * 128;

    frag_cd acc[2][4];
    #pragma unroll
    for (int i = 0; i < 2; i++)
        #pragma unroll
        for (int j = 0; j < 4; j++) acc[i][j] = (frag_cd){0.f, 0.f, 0.f, 0.f};

    const int wm = (w >> 1) * 32, wn = (w & 1) * 64;

    for (int k0 = 0; k0 < D_MODEL; k0 += BK) {
        __syncthreads();
        #pragma unroll
        for (int it = 0; it < 2; ++it) {
            int c = it * 256 + tid;
            int r = c >> 3, c8 = c & 7;
            const u16* ga = A + (size_t)(m0 + r) * D_MODEL + k0 + c8 * 8;
            char* la = (char*)As + (it * 256 + w * 64) * 16;
            __builtin_amdgcn_global_load_lds((const __attribute__((address_space(1))) void*)ga,
                                             (__attribute__((address_space(3))) void*)la, 16, 0, 0);
        }
        #pragma unroll
        for (int it = 0; it < 4; ++it) {
            int c = it * 256 + tid;
            int r = c >> 3, c8 = c & 7;
            const u16* gb = Wt + (size_t)(n0 + r) * D_MODEL + k0 + c8 * 8;
            char* lb = (char*)Bs + (it * 256 + w * 64) * 16;
            __builtin_amdgcn_global_load_lds((const __attribute__((address_space(1))) void*)gb,
                                             (__attribute__((address_space(3))) void*)lb, 16, 0, 0);
        }
        __syncthreads();

        #pragma unroll
        for (int kc = 0; kc < 2; ++kc) {
            frag_ab av[2], bvv[4];
            #pragma unroll
            for (int i = 0; i < 2; i++)
                av[i] = *(const frag_ab*)&As[(wm + i * 16 + lrow) * BK + kc * 32 + lquad * 8];
            #pragma unroll
            for (int j = 0; j < 4; j++)
                bvv[j] = *(const frag_ab*)&Bs[(wn + j * 16 + lrow) * BK + kc * 32 + lquad * 8];
            #pragma unroll
            for (int i = 0; i < 2; i++)
                #pragma unroll
                for (int j = 0; j < 4; j++)
                    acc[i][j] = __builtin_amdgcn_mfma_f32_16x16x32_bf16(av[i], bvv[j], acc[i][j], 0, 0, 0);
        }
    }

    #pragma unroll
    for (int j = 0; j < 4; j++) {
        int gn = n0 + wn + j * 16 + lrow;
        float bvf = bias[gn];
        #pragma unroll
        for (int i = 0; i < 2; i++)
            #pragma unroll
            for (int rr = 0; rr < 4; ++rr) {
                int gm = m0 + wm + i * 16 + lquad * 4 + rr;
                out[(size_t)gm * D_MODEL + gn] = acc[i][j][rr] + bvf;
            }
    }
}

// ---------------------------------------------------------------------------
// Attention, exp2 softmax, 128-key chunks, 512 threads (8 waves x 16 q-rows).
// Grid (16, 32). LDS: Ks[128][72] + Vs[64][136] + Ps[8][16][136] = 70.7 KB
// -> 2 blocks/CU, 16 waves/CU (4/SIMD).
// ---------------------------------------------------------------------------
__launch_bounds__(512, 4)
__global__ void attn_kernel(const u16* __restrict__ Q, const u16* __restrict__ K,
                            const u16* __restrict__ Vt, u16* __restrict__ O) {
    constexpr int SKK = 72;   // K row stride (64 d + pad)
    constexpr int SKV = 136;  // V/P row stride (128 keys + pad)
    __shared__ __attribute__((aligned(16))) u16 Ks[128 * SKK];
    __shared__ __attribute__((aligned(16))) u16 Vs[64 * SKV];
    __shared__ __attribute__((aligned(16))) u16 Ps[8 * 16 * SKV];

    const int tid = threadIdx.x;
    const int w = tid >> 6;           // 8 waves
    const int lane = tid & 63;
    const int lrow = lane & 15, lquad = lane >> 4;
    const int bh = blockIdx.y;
    const int q0 = blockIdx.x * 128;
    const size_t base = (size_t)bh * SEQ * HDIM;
    const u16* Qg = Q + base;
    const u16* Kg = K + base;
    const u16* Vg = Vt + base;  // [d][s]

    // Q fragments: wave handles rows q0 + w*16 .. +15
    frag_ab qf[2];
    #pragma unroll
    for (int kc = 0; kc < 2; ++kc)
        qf[kc] = *(const frag_ab*)&Qg[(size_t)(q0 + w * 16 + lrow) * HDIM + kc * 32 + lquad * 8];

    frag_cd accO[4], lacc;
    lacc = (frag_cd){0.f, 0.f, 0.f, 0.f};
    #pragma unroll
    for (int df = 0; df < 4; df++) accO[df] = (frag_cd){0.f, 0.f, 0.f, 0.f};
    frag_ab ones;
    #pragma unroll
    for (int t = 0; t < 8; ++t) ones[t] = (short)0x3F80;  // bf16 1.0

    u16* Pw = Ps + w * 16 * SKV;

    for (int kt = 0; kt < SEQ / 128; ++kt) {
        __syncthreads();
        #pragma unroll
        for (int it = 0; it < 2; ++it) {
            int c = it * 512 + tid;
            int rk = c >> 3, ck = (c & 7) * 8;
            *(uint4*)&Ks[rk * SKK + ck] = *(const uint4*)&Kg[(size_t)(kt * 128 + rk) * HDIM + ck];
            int rv = c >> 4, cv = (c & 15) * 8;
            *(uint4*)&Vs[rv * SKV + cv] = *(const uint4*)&Vg[(size_t)rv * SEQ + kt * 128 + cv];
        }
        __syncthreads();

        // scores: 16q x 128key per wave
        frag_cd sc[8];
        #pragma unroll
        for (int nf = 0; nf < 8; nf++) sc[nf] = (frag_cd){0.f, 0.f, 0.f, 0.f};
        #pragma unroll
        for (int kc = 0; kc < 2; ++kc) {
            #pragma unroll
            for (int nf = 0; nf < 8; nf++) {
                frag_ab kf = *(const frag_ab*)&Ks[(nf * 16 + lrow) * SKK + kc * 32 + lquad * 8];
                sc[nf] = __builtin_amdgcn_mfma_f32_16x16x32_bf16(qf[kc], kf, sc[nf], 0, 0, 0);
            }
        }

        // p = 2^s -> Pw[q][key] (C-layout scatter)
        #pragma unroll
        for (int nf = 0; nf < 8; nf++)
            #pragma unroll
            for (int i = 0; i < 4; i++)
                Pw[(lquad * 4 + i) * SKV + nf * 16 + lrow] = f2u_fast(exp2f(sc[nf][i]));

        // PV + rowsum over 128 keys
        #pragma unroll
        for (int kc = 0; kc < 4; ++kc) {
            frag_ab pf = *(const frag_ab*)&Pw[lrow * SKV + kc * 32 + lquad * 8];
            lacc = __builtin_amdgcn_mfma_f32_16x16x32_bf16(pf, ones, lacc, 0, 0, 0);
            #pragma unroll
            for (int df = 0; df < 4; df++) {
                frag_ab vf = *(const frag_ab*)&Vs[(df * 16 + lrow) * SKV + kc * 32 + lquad * 8];
                accO[df] = __builtin_amdgcn_mfma_f32_16x16x32_bf16(pf, vf, accO[df], 0, 0, 0);
            }
        }
    }

    const int b = bh >> 4, h = bh & (NHEAD - 1);
    #pragma unroll
    for (int df = 0; df < 4; df++)
        #pragma unroll
        for (int i = 0; i < 4; i++) {
            int s = q0 + w * 16 + lquad * 4 + i;
            int d = df * 16 + lrow;
            O[((size_t)(b * SEQ + s)) * D_MODEL + h * HDIM + d] = f2u(accO[df][i] / lacc[i]);
        }
}

// ---------------------------------------------------------------------------
// Workspace (u16 elems): xb [0,4M) | Wt 4 slabs [4M,8M) | Q,K [8M,16M)
//                        Vt [16M,20M) | attn-out [20M,24M)   = 48 MB
// ---------------------------------------------------------------------------
extern "C" void kernel_launch(void* const* d_in, const int* in_sizes, int n_in,
                              void* d_out, int out_size, void* d_ws, size_t ws_size,
                              hipStream_t stream) {
    const float* x  = (const float*)d_in[0];
    const float* Wq = (const float*)d_in[1];
    const float* bq = (const float*)d_in[2];
    const float* Wk = (const float*)d_in[3];
    const float* bk = (const float*)d_in[4];
    const float* Wv = (const float*)d_in[5];
    const float* bv = (const float*)d_in[6];
    const float* Wo = (const float*)d_in[7];
    const float* bo = (const float*)d_in[8];

    u16* ws = (u16*)d_ws;
    const size_t WSZ = (size_t)D_MODEL * D_MODEL;    // 1M elems
    const size_t TSZ = (size_t)MTOT * D_MODEL;       // 4M elems
    u16* xb  = ws;
    u16* Wt  = ws + 4 * WSZ;
    u16* QKw = ws + 8 * WSZ;        // Q slab 0, K slab 1
    u16* Vtw = QKw + 2 * TSZ;
    u16* Aw  = Vtw + TSZ;

    prep<<<dim3(32, 32, 5), dim3(32, 8), 0, stream>>>(Wq, Wk, Wv, Wo, x, Wt, xb);
    gemm_qkvt<<<dim3(768), 256, 0, stream>>>(xb, Wt, bq, bk, bv, QKw, Vtw);
    attn_kernel<<<dim3(16, 32), 512, 0, stream>>>(QKw, QKw + TSZ, Vtw, Aw);
    gemm_out<<<dim3(8, 64), 256, 0, stream>>>(Aw, Wt + 3 * WSZ, bo, (float*)d_out);
}

// Round 8
// 221.476 us; speedup vs baseline: 1.2533x; 1.0075x over previous
//
#include <hip/hip_runtime.h>
#include <hip/hip_bf16.h>

// MultiBertAttention fp32 I/O, bf16 MFMA internals.
// R8: attn rewritten transposed (S^T = K.Q^T): the S^T C-layout (lane=q col,
//     keys=quad*4+i) IS the B-operand layout of mfma_f32_16x16x16_bf16, so
//     exp(P) feeds PV directly from registers -> NO P LDS round-trip, no
//     conflicted scalar writes, no ones-MFMA (rowsum = in-reg adds + 2 shfl).
//     R7 was LDS-throughput-bound (770 LDS cyc vs 180 MFMA cyc per wave-iter).
//     prep / gemm_qkvt / gemm_out unchanged from R7.

typedef unsigned short u16;

#define D_MODEL 1024
#define NHEAD 16
#define HDIM 64
#define BATCH 2
#define SEQ 2048
#define MTOT (BATCH * SEQ)  // 4096

#define QSCALE 0.18033688011112042f  // (1/8) * log2(e)

using frag_ab = __attribute__((ext_vector_type(8))) short;  // 8 bf16 (16x16x32 A/B)
using frag_s4 = __attribute__((ext_vector_type(4))) short;  // 4 bf16 (16x16x16 A/B)
using frag_cd = __attribute__((ext_vector_type(4))) float;  // 4 fp32

__device__ __forceinline__ u16 f2u(float f) {  // RNE fp32->bf16
    union { float f; unsigned int i; } x;
    x.f = f;
    unsigned int r = x.i + 0x7fffu + ((x.i >> 16) & 1u);
    return (u16)(r >> 16);
}
__device__ __forceinline__ unsigned int pk2(float a, float b) {  // 2xbf16 packed, RNTA
    union { float f; unsigned int i; } x, y;
    x.f = a; y.f = b;
    return ((x.i + 0x8000u) >> 16) | (((y.i + 0x8000u) >> 16) << 16);
}

// ---------------------------------------------------------------------------
// prep: z<4 -> Wt[z][n][k] = bf16(W_z[k][n]); z==4 -> xb = bf16(x).
// ---------------------------------------------------------------------------
__global__ void prep(const float* __restrict__ W0, const float* __restrict__ W1,
                     const float* __restrict__ W2, const float* __restrict__ W3,
                     const float* __restrict__ X, u16* __restrict__ Wt,
                     u16* __restrict__ Xb) {
    const int z = blockIdx.z;
    const int tx = threadIdx.x, ty = threadIdx.y;
    if (z < 4) {
        __shared__ u16 t[32][33];
        const float* W = (z == 0) ? W0 : (z == 1) ? W1 : (z == 2) ? W2 : W3;
        u16* o = Wt + (size_t)z * D_MODEL * D_MODEL;
        int n0 = blockIdx.x * 32, k0 = blockIdx.y * 32;
        #pragma unroll
        for (int i = ty; i < 32; i += 8) t[i][tx] = f2u(W[(size_t)(k0 + i) * D_MODEL + n0 + tx]);
        __syncthreads();
        #pragma unroll
        for (int i = ty; i < 32; i += 8) o[(size_t)(n0 + i) * D_MODEL + k0 + tx] = t[tx][i];
    } else {
        int tid = ty * 32 + tx;
        size_t base = ((size_t)(blockIdx.y * 32 + blockIdx.x) * 256 + tid) * 16;
        #pragma unroll
        for (int c = 0; c < 4; ++c) {
            float4 v = *(const float4*)&X[base + c * 4];
            ushort4 o;
            o.x = f2u(v.x); o.y = f2u(v.y); o.z = f2u(v.z); o.w = f2u(v.w);
            *(ushort4*)&Xb[base + c * 4] = o;
        }
    }
}

// ---------------------------------------------------------------------------
// Fused QKV + V^T GEMM, 768 blocks (1D). 128x128 tile, BK=64, global_load_lds.
// ---------------------------------------------------------------------------
__launch_bounds__(256, 3)
__global__ void gemm_qkvt(const u16* __restrict__ xb, const u16* __restrict__ Wt,
                          const float* __restrict__ bq, const float* __restrict__ bk,
                          const float* __restrict__ bv, u16* __restrict__ QKw,
                          u16* __restrict__ Vtw) {
    constexpr int BK = 64;
    __shared__ __attribute__((aligned(16))) u16 As[128 * BK];
    __shared__ __attribute__((aligned(16))) u16 Bs[128 * BK];

    const int tid = threadIdx.x;
    const int w = tid >> 6;
    const int lane = tid & 63;
    const int lrow = lane & 15, lquad = lane >> 4;
    const size_t WSZ = (size_t)D_MODEL * D_MODEL;

    const int bid = blockIdx.x;
    const bool vt = bid >= 512;
    const int z = vt ? 2 : (bid >> 8);
    const int t = vt ? (bid - 512) : (bid & 255);
    const int n0 = vt ? (t & 31) * 128 : (t & 7) * 128;
    const int m0 = vt ? (t >> 5) * 128 : (t >> 3) * 128;
    const u16* Ap = vt ? (Wt + 2 * WSZ) : xb;
    const u16* Bp = vt ? xb : (Wt + (size_t)z * WSZ);
    const float* bias = vt ? bv : (z ? bk : bq);

    frag_cd acc[4][4];
    #pragma unroll
    for (int i = 0; i < 4; i++)
        #pragma unroll
        for (int j = 0; j < 4; j++) acc[i][j] = (frag_cd){0.f, 0.f, 0.f, 0.f};

    const int wm = (w >> 1) * 64, wn = (w & 1) * 64;

    for (int k0 = 0; k0 < D_MODEL; k0 += BK) {
        __syncthreads();
        #pragma unroll
        for (int it = 0; it < 4; ++it) {
            int c = it * 256 + tid;
            int r = c >> 3, c8 = c & 7;
            const u16* ga = Ap + (size_t)(m0 + r) * D_MODEL + k0 + c8 * 8;
            char* la = (char*)As + (it * 256 + w * 64) * 16;
            __builtin_amdgcn_global_load_lds((const __attribute__((address_space(1))) void*)ga,
                                             (__attribute__((address_space(3))) void*)la, 16, 0, 0);
            const u16* gb = Bp + (size_t)(n0 + r) * D_MODEL + k0 + c8 * 8;
            char* lb = (char*)Bs + (it * 256 + w * 64) * 16;
            __builtin_amdgcn_global_load_lds((const __attribute__((address_space(1))) void*)gb,
                                             (__attribute__((address_space(3))) void*)lb, 16, 0, 0);
        }
        __syncthreads();

        #pragma unroll
        for (int kc = 0; kc < 2; ++kc) {
            frag_ab av[4], bvv[4];
            #pragma unroll
            for (int i = 0; i < 4; i++)
                av[i] = *(const frag_ab*)&As[(wm + i * 16 + lrow) * BK + kc * 32 + lquad * 8];
            #pragma unroll
            for (int j = 0; j < 4; j++)
                bvv[j] = *(const frag_ab*)&Bs[(wn + j * 16 + lrow) * BK + kc * 32 + lquad * 8];
            #pragma unroll
            for (int i = 0; i < 4; i++)
                #pragma unroll
                for (int j = 0; j < 4; j++)
                    acc[i][j] = __builtin_amdgcn_mfma_f32_16x16x32_bf16(av[i], bvv[j], acc[i][j], 0, 0, 0);
        }
    }

    const float scale = (!vt && z == 0) ? QSCALE : 1.0f;
    #pragma unroll
    for (int j = 0; j < 4; j++) {
        int gn = n0 + wn + j * 16 + lrow;
        #pragma unroll
        for (int i = 0; i < 4; i++) {
            #pragma unroll
            for (int rr = 0; rr < 4; ++rr) {
                int gm = m0 + wm + i * 16 + lquad * 4 + rr;
                if (!vt) {
                    float v = (acc[i][j][rr] + bias[gn]) * scale;
                    u16* oz = QKw + (size_t)z * ((size_t)MTOT * D_MODEL);
                    int b = gm >> 11, s = gm & (SEQ - 1);
                    int h = gn >> 6, d = gn & (HDIM - 1);
                    oz[(((size_t)(b * NHEAD + h)) * SEQ + s) * HDIM + d] = f2u(v);
                } else {
                    float v = acc[i][j][rr] + bias[gm];
                    int h = gm >> 6, d = gm & (HDIM - 1);
                    int b = gn >> 11, s = gn & (SEQ - 1);
                    Vtw[(((size_t)(b * NHEAD + h)) * HDIM + d) * SEQ + s] = f2u(v);
                }
            }
        }
    }
}

// ---------------------------------------------------------------------------
// Out projection: 64x128 tile (512 blocks), fp32 store.
// ---------------------------------------------------------------------------
__launch_bounds__(256, 2)
__global__ void gemm_out(const u16* __restrict__ A, const u16* __restrict__ Wt,
                         const float* __restrict__ bias, float* __restrict__ out) {
    constexpr int BK = 64;
    __shared__ __attribute__((aligned(16))) u16 As[64 * BK];
    __shared__ __attribute__((aligned(16))) u16 Bs[128 * BK];

    const int tid = threadIdx.x;
    const int w = tid >> 6;
    const int lane = tid & 63;
    const int lrow = lane & 15, lquad = lane >> 4;
    const int m0 = blockIdx.y * 64, n0 = blockIdx.x * 128;

    frag_cd acc[2][4];
    #pragma unroll
    for (int i = 0; i < 2; i++)
        #pragma unroll
        for (int j = 0; j < 4; j++) acc[i][j] = (frag_cd){0.f, 0.f, 0.f, 0.f};

    const int wm = (w >> 1) * 32, wn = (w & 1) * 64;

    for (int k0 = 0; k0 < D_MODEL; k0 += BK) {
        __syncthreads();
        #pragma unroll
        for (int it = 0; it < 2; ++it) {
            int c = it * 256 + tid;
            int r = c >> 3, c8 = c & 7;
            const u16* ga = A + (size_t)(m0 + r) * D_MODEL + k0 + c8 * 8;
            char* la = (char*)As + (it * 256 + w * 64) * 16;
            __builtin_amdgcn_global_load_lds((const __attribute__((address_space(1))) void*)ga,
                                             (__attribute__((address_space(3))) void*)la, 16, 0, 0);
        }
        #pragma unroll
        for (int it = 0; it < 4; ++it) {
            int c = it * 256 + tid;
            int r = c >> 3, c8 = c & 7;
            const u16* gb = Wt + (size_t)(n0 + r) * D_MODEL + k0 + c8 * 8;
            char* lb = (char*)Bs + (it * 256 + w * 64) * 16;
            __builtin_amdgcn_global_load_lds((const __attribute__((address_space(1))) void*)gb,
                                             (__attribute__((address_space(3))) void*)lb, 16, 0, 0);
        }
        __syncthreads();

        #pragma unroll
        for (int kc = 0; kc < 2; ++kc) {
            frag_ab av[2], bvv[4];
            #pragma unroll
            for (int i = 0; i < 2; i++)
                av[i] = *(const frag_ab*)&As[(wm + i * 16 + lrow) * BK + kc * 32 + lquad * 8];
            #pragma unroll
            for (int j = 0; j < 4; j++)
                bvv[j] = *(const frag_ab*)&Bs[(wn + j * 16 + lrow) * BK + kc * 32 + lquad * 8];
            #pragma unroll
            for (int i = 0; i < 2; i++)
                #pragma unroll
                for (int j = 0; j < 4; j++)
                    acc[i][j] = __builtin_amdgcn_mfma_f32_16x16x32_bf16(av[i], bvv[j], acc[i][j], 0, 0, 0);
        }
    }

    #pragma unroll
    for (int j = 0; j < 4; j++) {
        int gn = n0 + wn + j * 16 + lrow;
        float bvf = bias[gn];
        #pragma unroll
        for (int i = 0; i < 2; i++)
            #pragma unroll
            for (int rr = 0; rr < 4; ++rr) {
                int gm = m0 + wm + i * 16 + lquad * 4 + rr;
                out[(size_t)gm * D_MODEL + gn] = acc[i][j][rr] + bvf;
            }
    }
}

// ---------------------------------------------------------------------------
// Attention (transposed, register-resident P). Grid (16,32), 512 thr (8 waves
// x 16 q). Per 128-key tile:
//   S^T = K.Q^T via mfma_16x16x32 (A=K from Ks, B=Q regs) -> lane = one q col,
//   keys = mf*16 + lquad*4 + i.  p = exp2(s) in regs; rowsum = reg adds +
//   shfl_xor(16,32).  Pack p -> short4 = B-operand of mfma_16x16x16_bf16;
//   PV: O^T[d][q] += V^T(A, b64 from Vs) . P^T(B, regs).  No P LDS traffic.
// LDS: Ks 128x72 + Vs 64x136 = 35.8 KB.
// ---------------------------------------------------------------------------
__launch_bounds__(512, 4)
__global__ void attn_kernel(const u16* __restrict__ Q, const u16* __restrict__ K,
                            const u16* __restrict__ Vt, u16* __restrict__ O) {
    constexpr int SKK = 72;   // K row stride (64 d + pad)
    constexpr int SKV = 136;  // V row stride (128 keys + pad)
    __shared__ __attribute__((aligned(16))) u16 Ks[128 * SKK];
    __shared__ __attribute__((aligned(16))) u16 Vs[64 * SKV];

    const int tid = threadIdx.x;
    const int w = tid >> 6;           // 8 waves
    const int lane = tid & 63;
    const int lrow = lane & 15, lquad = lane >> 4;
    const int bh = blockIdx.y;
    const int q0 = blockIdx.x * 128;
    const size_t base = (size_t)bh * SEQ * HDIM;
    const u16* Qg = Q + base;
    const u16* Kg = K + base;
    const u16* Vg = Vt + base;  // [d][s]

    // Q as B-operand of 16x16x32: lane holds q = lrow, d = kc*32 + lquad*8 + j
    frag_ab qf[2];
    #pragma unroll
    for (int kc = 0; kc < 2; ++kc)
        qf[kc] = *(const frag_ab*)&Qg[(size_t)(q0 + w * 16 + lrow) * HDIM + kc * 32 + lquad * 8];

    frag_cd accOT[4];   // O^T: lane q = lrow, d = df*16 + lquad*4 + i
    #pragma unroll
    for (int df = 0; df < 4; df++) accOT[df] = (frag_cd){0.f, 0.f, 0.f, 0.f};
    float lacc = 0.f;   // softmax denom for this lane's q (key-subset, reduced later)

    for (int kt = 0; kt < SEQ / 128; ++kt) {
        __syncthreads();
        #pragma unroll
        for (int it = 0; it < 2; ++it) {
            int c = it * 512 + tid;
            int rk = c >> 3, ck = (c & 7) * 8;
            *(uint4*)&Ks[rk * SKK + ck] = *(const uint4*)&Kg[(size_t)(kt * 128 + rk) * HDIM + ck];
            int rv = c >> 4, cv = (c & 15) * 8;
            *(uint4*)&Vs[rv * SKV + cv] = *(const uint4*)&Vg[(size_t)rv * SEQ + kt * 128 + cv];
        }
        __syncthreads();

        // S^T[key][q]: A = K (m = key), B = Q. C-layout: col=q=lrow, row=key=mf*16+lquad*4+i
        frag_cd sc[8];
        #pragma unroll
        for (int mf = 0; mf < 8; mf++) sc[mf] = (frag_cd){0.f, 0.f, 0.f, 0.f};
        #pragma unroll
        for (int kc = 0; kc < 2; ++kc)
            #pragma unroll
            for (int mf = 0; mf < 8; mf++) {
                frag_ab kf = *(const frag_ab*)&Ks[(mf * 16 + lrow) * SKK + kc * 32 + lquad * 8];
                sc[mf] = __builtin_amdgcn_mfma_f32_16x16x32_bf16(kf, qf[kc], sc[mf], 0, 0, 0);
            }

        // p = 2^s in-register; rowsum partial; pack to 16x16x16 B-operand layout
        frag_s4 pk[8];
        float rs = 0.f;
        #pragma unroll
        for (int mf = 0; mf < 8; mf++) {
            float e0 = exp2f(sc[mf][0]), e1 = exp2f(sc[mf][1]);
            float e2 = exp2f(sc[mf][2]), e3 = exp2f(sc[mf][3]);
            rs += (e0 + e1) + (e2 + e3);
            union { frag_s4 s; unsigned int u[2]; } pu;
            pu.u[0] = pk2(e0, e1);
            pu.u[1] = pk2(e2, e3);
            pk[mf] = pu.s;
        }
        rs += __shfl_xor(rs, 16);
        rs += __shfl_xor(rs, 32);
        lacc += rs;

        // O^T += V^T . P^T : A = V^T (m=d, k=key, b64 from Vs), B = pk (regs)
        #pragma unroll
        for (int mf = 0; mf < 8; mf++)
            #pragma unroll
            for (int df = 0; df < 4; df++) {
                frag_s4 vf = *(const frag_s4*)&Vs[(df * 16 + lrow) * SKV + mf * 16 + lquad * 4];
                accOT[df] = __builtin_amdgcn_mfma_f32_16x16x16bf16_1k(vf, pk[mf], accOT[df], 0, 0, 0);
            }
    }

    // epilogue: lane owns one q entirely -> single reciprocal; b64 stores
    const int b = bh >> 4, h = bh & (NHEAD - 1);
    const int s = q0 + w * 16 + lrow;
    const float inv = 1.0f / lacc;
    u16* orow = O + ((size_t)(b * SEQ + s)) * D_MODEL + h * HDIM;
    #pragma unroll
    for (int df = 0; df < 4; df++) {
        ushort4 o;
        o.x = f2u(accOT[df][0] * inv);
        o.y = f2u(accOT[df][1] * inv);
        o.z = f2u(accOT[df][2] * inv);
        o.w = f2u(accOT[df][3] * inv);
        *(ushort4*)&orow[df * 16 + lquad * 4] = o;
    }
}

// ---------------------------------------------------------------------------
// Workspace (u16 elems): xb [0,4M) | Wt 4 slabs [4M,8M) | Q,K [8M,16M)
//                        Vt [16M,20M) | attn-out [20M,24M)   = 48 MB
// ---------------------------------------------------------------------------
extern "C" void kernel_launch(void* const* d_in, const int* in_sizes, int n_in,
                              void* d_out, int out_size, void* d_ws, size_t ws_size,
                              hipStream_t stream) {
    const float* x  = (const float*)d_in[0];
    const float* Wq = (const float*)d_in[1];
    const float* bq = (const float*)d_in[2];
    const float* Wk = (const float*)d_in[3];
    const float* bk = (const float*)d_in[4];
    const float* Wv = (const float*)d_in[5];
    const float* bv = (const float*)d_in[6];
    const float* Wo = (const float*)d_in[7];
    const float* bo = (const float*)d_in[8];

    u16* ws = (u16*)d_ws;
    const size_t WSZ = (size_t)D_MODEL * D_MODEL;    // 1M elems
    const size_t TSZ = (size_t)MTOT * D_MODEL;       // 4M elems
    u16* xb  = ws;
    u16* Wt  = ws + 4 * WSZ;
    u16* QKw = ws + 8 * WSZ;        // Q slab 0, K slab 1
    u16* Vtw = QKw + 2 * TSZ;
    u16* Aw  = Vtw + TSZ;

    prep<<<dim3(32, 32, 5), dim3(32, 8), 0, stream>>>(Wq, Wk, Wv, Wo, x, Wt, xb);
    gemm_qkvt<<<dim3(768), 256, 0, stream>>>(xb, Wt, bq, bk, bv, QKw, Vtw);
    attn_kernel<<<dim3(16, 32), 512, 0, stream>>>(QKw, QKw + TSZ, Vtw, Aw);
    gemm_out<<<dim3(8, 64), 256, 0, stream>>>(Aw, Wt + 3 * WSZ, bo, (float*)d_out);
}

// Round 9
// 219.409 us; speedup vs baseline: 1.2651x; 1.0094x over previous
//
#include <hip/hip_runtime.h>
#include <hip/hip_bf16.h>

// MultiBertAttention fp32 I/O, bf16 MFMA internals.
// R9: R8 structure (transposed S^T, register-resident P) with fixes:
//     (1) Vs XOR-swizzle (stride 128, chunk^=(d&7)) -> conflict-free b64 V reads
//         (R8's SKV=136 pattern was 2x-over-minimum, conflicts 12.6M),
//     (2) rowsum shfl_xor hoisted out of the K-loop (additive partials),
//     (3) v_cvt_pk_bf16_f32 via __float22bfloat162_rn for P pack + epilogue.
//     prep / gemm_qkvt / gemm_out unchanged.

typedef unsigned short u16;

#define D_MODEL 1024
#define NHEAD 16
#define HDIM 64
#define BATCH 2
#define SEQ 2048
#define MTOT (BATCH * SEQ)  // 4096

#define QSCALE 0.18033688011112042f  // (1/8) * log2(e)

using frag_ab = __attribute__((ext_vector_type(8))) short;  // 8 bf16 (16x16x32 A/B)
using frag_s4 = __attribute__((ext_vector_type(4))) short;  // 4 bf16 (16x16x16 A/B)
using frag_cd = __attribute__((ext_vector_type(4))) float;  // 4 fp32

__device__ __forceinline__ u16 f2u(float f) {  // RNE fp32->bf16
    union { float f; unsigned int i; } x;
    x.f = f;
    unsigned int r = x.i + 0x7fffu + ((x.i >> 16) & 1u);
    return (u16)(r >> 16);
}
__device__ __forceinline__ unsigned int pkrn(float a, float b) {  // v_cvt_pk_bf16_f32
    union { __hip_bfloat162 h; unsigned int u; } c;
    c.h = __float22bfloat162_rn(float2{a, b});
    return c.u;
}

// ---------------------------------------------------------------------------
// prep: z<4 -> Wt[z][n][k] = bf16(W_z[k][n]); z==4 -> xb = bf16(x).
// ---------------------------------------------------------------------------
__global__ void prep(const float* __restrict__ W0, const float* __restrict__ W1,
                     const float* __restrict__ W2, const float* __restrict__ W3,
                     const float* __restrict__ X, u16* __restrict__ Wt,
                     u16* __restrict__ Xb) {
    const int z = blockIdx.z;
    const int tx = threadIdx.x, ty = threadIdx.y;
    if (z < 4) {
        __shared__ u16 t[32][33];
        const float* W = (z == 0) ? W0 : (z == 1) ? W1 : (z == 2) ? W2 : W3;
        u16* o = Wt + (size_t)z * D_MODEL * D_MODEL;
        int n0 = blockIdx.x * 32, k0 = blockIdx.y * 32;
        #pragma unroll
        for (int i = ty; i < 32; i += 8) t[i][tx] = f2u(W[(size_t)(k0 + i) * D_MODEL + n0 + tx]);
        __syncthreads();
        #pragma unroll
        for (int i = ty; i < 32; i += 8) o[(size_t)(n0 + i) * D_MODEL + k0 + tx] = t[tx][i];
    } else {
        int tid = ty * 32 + tx;
        size_t base = ((size_t)(blockIdx.y * 32 + blockIdx.x) * 256 + tid) * 16;
        #pragma unroll
        for (int c = 0; c < 4; ++c) {
            float4 v = *(const float4*)&X[base + c * 4];
            ushort4 o;
            o.x = f2u(v.x); o.y = f2u(v.y); o.z = f2u(v.z); o.w = f2u(v.w);
            *(ushort4*)&Xb[base + c * 4] = o;
        }
    }
}

// ---------------------------------------------------------------------------
// Fused QKV + V^T GEMM, 768 blocks (1D). 128x128 tile, BK=64, global_load_lds.
// ---------------------------------------------------------------------------
__launch_bounds__(256, 3)
__global__ void gemm_qkvt(const u16* __restrict__ xb, const u16* __restrict__ Wt,
                          const float* __restrict__ bq, const float* __restrict__ bk,
                          const float* __restrict__ bv, u16* __restrict__ QKw,
                          u16* __restrict__ Vtw) {
    constexpr int BK = 64;
    __shared__ __attribute__((aligned(16))) u16 As[128 * BK];
    __shared__ __attribute__((aligned(16))) u16 Bs[128 * BK];

    const int tid = threadIdx.x;
    const int w = tid >> 6;
    const int lane = tid & 63;
    const int lrow = lane & 15, lquad = lane >> 4;
    const size_t WSZ = (size_t)D_MODEL * D_MODEL;

    const int bid = blockIdx.x;
    const bool vt = bid >= 512;
    const int z = vt ? 2 : (bid >> 8);
    const int t = vt ? (bid - 512) : (bid & 255);
    const int n0 = vt ? (t & 31) * 128 : (t & 7) * 128;
    const int m0 = vt ? (t >> 5) * 128 : (t >> 3) * 128;
    const u16* Ap = vt ? (Wt + 2 * WSZ) : xb;
    const u16* Bp = vt ? xb : (Wt + (size_t)z * WSZ);
    const float* bias = vt ? bv : (z ? bk : bq);

    frag_cd acc[4][4];
    #pragma unroll
    for (int i = 0; i < 4; i++)
        #pragma unroll
        for (int j = 0; j < 4; j++) acc[i][j] = (frag_cd){0.f, 0.f, 0.f, 0.f};

    const int wm = (w >> 1) * 64, wn = (w & 1) * 64;

    for (int k0 = 0; k0 < D_MODEL; k0 += BK) {
        __syncthreads();
        #pragma unroll
        for (int it = 0; it < 4; ++it) {
            int c = it * 256 + tid;
            int r = c >> 3, c8 = c & 7;
            const u16* ga = Ap + (size_t)(m0 + r) * D_MODEL + k0 + c8 * 8;
            char* la = (char*)As + (it * 256 + w * 64) * 16;
            __builtin_amdgcn_global_load_lds((const __attribute__((address_space(1))) void*)ga,
                                             (__attribute__((address_space(3))) void*)la, 16, 0, 0);
            const u16* gb = Bp + (size_t)(n0 + r) * D_MODEL + k0 + c8 * 8;
            char* lb = (char*)Bs + (it * 256 + w * 64) * 16;
            __builtin_amdgcn_global_load_lds((const __attribute__((address_space(1))) void*)gb,
                                             (__attribute__((address_space(3))) void*)lb, 16, 0, 0);
        }
        __syncthreads();

        #pragma unroll
        for (int kc = 0; kc < 2; ++kc) {
            frag_ab av[4], bvv[4];
            #pragma unroll
            for (int i = 0; i < 4; i++)
                av[i] = *(const frag_ab*)&As[(wm + i * 16 + lrow) * BK + kc * 32 + lquad * 8];
            #pragma unroll
            for (int j = 0; j < 4; j++)
                bvv[j] = *(const frag_ab*)&Bs[(wn + j * 16 + lrow) * BK + kc * 32 + lquad * 8];
            #pragma unroll
            for (int i = 0; i < 4; i++)
                #pragma unroll
                for (int j = 0; j < 4; j++)
                    acc[i][j] = __builtin_amdgcn_mfma_f32_16x16x32_bf16(av[i], bvv[j], acc[i][j], 0, 0, 0);
        }
    }

    const float scale = (!vt && z == 0) ? QSCALE : 1.0f;
    #pragma unroll
    for (int j = 0; j < 4; j++) {
        int gn = n0 + wn + j * 16 + lrow;
        #pragma unroll
        for (int i = 0; i < 4; i++) {
            #pragma unroll
            for (int rr = 0; rr < 4; ++rr) {
                int gm = m0 + wm + i * 16 + lquad * 4 + rr;
                if (!vt) {
                    float v = (acc[i][j][rr] + bias[gn]) * scale;
                    u16* oz = QKw + (size_t)z * ((size_t)MTOT * D_MODEL);
                    int b = gm >> 11, s = gm & (SEQ - 1);
                    int h = gn >> 6, d = gn & (HDIM - 1);
                    oz[(((size_t)(b * NHEAD + h)) * SEQ + s) * HDIM + d] = f2u(v);
                } else {
                    float v = acc[i][j][rr] + bias[gm];
                    int h = gm >> 6, d = gm & (HDIM - 1);
                    int b = gn >> 11, s = gn & (SEQ - 1);
                    Vtw[(((size_t)(b * NHEAD + h)) * HDIM + d) * SEQ + s] = f2u(v);
                }
            }
        }
    }
}

// ---------------------------------------------------------------------------
// Out projection: 64x128 tile (512 blocks), fp32 store.
// ---------------------------------------------------------------------------
__launch_bounds__(256, 2)
__global__ void gemm_out(const u16* __restrict__ A, const u16* __restrict__ Wt,
                         const float* __restrict__ bias, float* __restrict__ out) {
    constexpr int BK = 64;
    __shared__ __attribute__((aligned(16))) u16 As[64 * BK];
    __shared__ __attribute__((aligned(16))) u16 Bs[128 * BK];

    const int tid = threadIdx.x;
    const int w = tid >> 6;
    const int lane = tid & 63;
    const int lrow = lane & 15, lquad = lane >> 4;
    const int m0 = blockIdx.y * 64, n0 = blockIdx.x * 128;

    frag_cd acc[2][4];
    #pragma unroll
    for (int i = 0; i < 2; i++)
        #pragma unroll
        for (int j = 0; j < 4; j++) acc[i][j] = (frag_cd){0.f, 0.f, 0.f, 0.f};

    const int wm = (w >> 1) * 32, wn = (w & 1) * 64;

    for (int k0 = 0; k0 < D_MODEL; k0 += BK) {
        __syncthreads();
        #pragma unroll
        for (int it = 0; it < 2; ++it) {
            int c = it * 256 + tid;
            int r = c >> 3, c8 = c & 7;
            const u16* ga = A + (size_t)(m0 + r) * D_MODEL + k0 + c8 * 8;
            char* la = (char*)As + (it * 256 + w * 64) * 16;
            __builtin_amdgcn_global_load_lds((const __attribute__((address_space(1))) void*)ga,
                                             (__attribute__((address_space(3))) void*)la, 16, 0, 0);
        }
        #pragma unroll
        for (int it = 0; it < 4; ++it) {
            int c = it * 256 + tid;
            int r = c >> 3, c8 = c & 7;
            const u16* gb = Wt + (size_t)(n0 + r) * D_MODEL + k0 + c8 * 8;
            char* lb = (char*)Bs + (it * 256 + w * 64) * 16;
            __builtin_amdgcn_global_load_lds((const __attribute__((address_space(1))) void*)gb,
                                             (__attribute__((address_space(3))) void*)lb, 16, 0, 0);
        }
        __syncthreads();

        #pragma unroll
        for (int kc = 0; kc < 2; ++kc) {
            frag_ab av[2], bvv[4];
            #pragma unroll
            for (int i = 0; i < 2; i++)
                av[i] = *(const frag_ab*)&As[(wm + i * 16 + lrow) * BK + kc * 32 + lquad * 8];
            #pragma unroll
            for (int j = 0; j < 4; j++)
                bvv[j] = *(const frag_ab*)&Bs[(wn + j * 16 + lrow) * BK + kc * 32 + lquad * 8];
            #pragma unroll
            for (int i = 0; i < 2; i++)
                #pragma unroll
                for (int j = 0; j < 4; j++)
                    acc[i][j] = __builtin_amdgcn_mfma_f32_16x16x32_bf16(av[i], bvv[j], acc[i][j], 0, 0, 0);
        }
    }

    #pragma unroll
    for (int j = 0; j < 4; j++) {
        int gn = n0 + wn + j * 16 + lrow;
        float bvf = bias[gn];
        #pragma unroll
        for (int i = 0; i < 2; i++)
            #pragma unroll
            for (int rr = 0; rr < 4; ++rr) {
                int gm = m0 + wm + i * 16 + lquad * 4 + rr;
                out[(size_t)gm * D_MODEL + gn] = acc[i][j][rr] + bvf;
            }
    }
}

// ---------------------------------------------------------------------------
// Attention (transposed, register-resident P). Grid (16,32), 512 thr (8 waves
// x 16 q). S^T = K.Q^T via mfma_16x16x32; p = exp2 in regs; P packed
// (v_cvt_pk_bf16_f32) feeds PV (O^T = V^T.P^T) via mfma_16x16x16 B-operand.
// Vs: stride 128 u16, XOR-swizzled 16B chunks (chunk ^= d&7) -> conflict-free
// b64 reads. Rowsum partials per-lane, reduced once in epilogue.
// LDS: Ks 128x72 + Vs 64x128 = 34.8 KB.
// ---------------------------------------------------------------------------
__launch_bounds__(512, 4)
__global__ void attn_kernel(const u16* __restrict__ Q, const u16* __restrict__ K,
                            const u16* __restrict__ Vt, u16* __restrict__ O) {
    constexpr int SKK = 72;   // K row stride (64 d + pad)
    __shared__ __attribute__((aligned(16))) u16 Ks[128 * SKK];
    __shared__ __attribute__((aligned(16))) u16 Vs[64 * 128];  // swizzled

    const int tid = threadIdx.x;
    const int w = tid >> 6;           // 8 waves
    const int lane = tid & 63;
    const int lrow = lane & 15, lquad = lane >> 4;
    const int bh = blockIdx.y;
    const int q0 = blockIdx.x * 128;
    const size_t base = (size_t)bh * SEQ * HDIM;
    const u16* Qg = Q + base;
    const u16* Kg = K + base;
    const u16* Vg = Vt + base;  // [d][s]

    // Q as B-operand of 16x16x32: lane holds q = lrow, d = kc*32 + lquad*8 + j
    frag_ab qf[2];
    #pragma unroll
    for (int kc = 0; kc < 2; ++kc)
        qf[kc] = *(const frag_ab*)&Qg[(size_t)(q0 + w * 16 + lrow) * HDIM + kc * 32 + lquad * 8];

    frag_cd accOT[4];   // O^T: lane q = lrow, d = df*16 + lquad*4 + i
    #pragma unroll
    for (int df = 0; df < 4; df++) accOT[df] = (frag_cd){0.f, 0.f, 0.f, 0.f};
    float lacc = 0.f;   // per-lane softmax denom partial (reduced in epilogue)

    for (int kt = 0; kt < SEQ / 128; ++kt) {
        __syncthreads();
        #pragma unroll
        for (int it = 0; it < 2; ++it) {
            int c = it * 512 + tid;
            int rk = c >> 3, ck = (c & 7) * 8;
            *(uint4*)&Ks[rk * SKK + ck] = *(const uint4*)&Kg[(size_t)(kt * 128 + rk) * HDIM + ck];
            int rv = c >> 4, gv = c & 15;   // row d, 16B chunk index
            *(uint4*)&Vs[rv * 128 + ((gv ^ (rv & 7)) << 3)] =
                *(const uint4*)&Vg[(size_t)rv * SEQ + kt * 128 + gv * 8];
        }
        __syncthreads();

        // S^T[key][q]: A = K (m=key), B = Q. C-layout: col=q=lrow, row=key=mf*16+lquad*4+i
        frag_cd sc[8];
        #pragma unroll
        for (int mf = 0; mf < 8; mf++) sc[mf] = (frag_cd){0.f, 0.f, 0.f, 0.f};
        #pragma unroll
        for (int kc = 0; kc < 2; ++kc)
            #pragma unroll
            for (int mf = 0; mf < 8; mf++) {
                frag_ab kf = *(const frag_ab*)&Ks[(mf * 16 + lrow) * SKK + kc * 32 + lquad * 8];
                sc[mf] = __builtin_amdgcn_mfma_f32_16x16x32_bf16(kf, qf[kc], sc[mf], 0, 0, 0);
            }

        // p = 2^s in-register; per-lane rowsum partial; pack via v_cvt_pk_bf16_f32
        frag_s4 pk[8];
        #pragma unroll
        for (int mf = 0; mf < 8; mf++) {
            float e0 = exp2f(sc[mf][0]), e1 = exp2f(sc[mf][1]);
            float e2 = exp2f(sc[mf][2]), e3 = exp2f(sc[mf][3]);
            lacc += (e0 + e1) + (e2 + e3);
            union { frag_s4 s; unsigned int u[2]; } pu;
            pu.u[0] = pkrn(e0, e1);
            pu.u[1] = pkrn(e2, e3);
            pk[mf] = pu.s;
        }

        // O^T += V^T . P^T : A = V^T (m=d, k=key, swizzled b64 from Vs), B = pk
        #pragma unroll
        for (int mf = 0; mf < 8; mf++)
            #pragma unroll
            for (int df = 0; df < 4; df++) {
                int dr = df * 16 + lrow;
                int g = 2 * mf + (lquad >> 1);
                frag_s4 vf = *(const frag_s4*)&Vs[dr * 128 + ((g ^ (dr & 7)) << 3) + (lquad & 1) * 4];
                accOT[df] = __builtin_amdgcn_mfma_f32_16x16x16bf16_1k(vf, pk[mf], accOT[df], 0, 0, 0);
            }
    }

    // reduce rowsum across the 4 quads holding this q (lanes lrow, lrow+16, +32, +48)
    lacc += __shfl_xor(lacc, 16);
    lacc += __shfl_xor(lacc, 32);

    // epilogue: lane owns one q -> single reciprocal; b64 stores (packed cvt)
    const int b = bh >> 4, h = bh & (NHEAD - 1);
    const int s = q0 + w * 16 + lrow;
    const float inv = 1.0f / lacc;
    u16* orow = O + ((size_t)(b * SEQ + s)) * D_MODEL + h * HDIM;
    #pragma unroll
    for (int df = 0; df < 4; df++) {
        union { unsigned int u[2]; ushort4 s4; } o;
        o.u[0] = pkrn(accOT[df][0] * inv, accOT[df][1] * inv);
        o.u[1] = pkrn(accOT[df][2] * inv, accOT[df][3] * inv);
        *(ushort4*)&orow[df * 16 + lquad * 4] = o.s4;
    }
}

// ---------------------------------------------------------------------------
// Workspace (u16 elems): xb [0,4M) | Wt 4 slabs [4M,8M) | Q,K [8M,16M)
//                        Vt [16M,20M) | attn-out [20M,24M)   = 48 MB
// ---------------------------------------------------------------------------
extern "C" void kernel_launch(void* const* d_in, const int* in_sizes, int n_in,
                              void* d_out, int out_size, void* d_ws, size_t ws_size,
                              hipStream_t stream) {
    const float* x  = (const float*)d_in[0];
    const float* Wq = (const float*)d_in[1];
    const float* bq = (const float*)d_in[2];
    const float* Wk = (const float*)d_in[3];
    const float* bk = (const float*)d_in[4];
    const float* Wv = (const float*)d_in[5];
    const float* bv = (const float*)d_in[6];
    const float* Wo = (const float*)d_in[7];
    const float* bo = (const float*)d_in[8];

    u16* ws = (u16*)d_ws;
    const size_t WSZ = (size_t)D_MODEL * D_MODEL;    // 1M elems
    const size_t TSZ = (size_t)MTOT * D_MODEL;       // 4M elems
    u16* xb  = ws;
    u16* Wt  = ws + 4 * WSZ;
    u16* QKw = ws + 8 * WSZ;        // Q slab 0, K slab 1
    u16* Vtw = QKw + 2 * TSZ;
    u16* Aw  = Vtw + TSZ;

    prep<<<dim3(32, 32, 5), dim3(32, 8), 0, stream>>>(Wq, Wk, Wv, Wo, x, Wt, xb);
    gemm_qkvt<<<dim3(768), 256, 0, stream>>>(xb, Wt, bq, bk, bv, QKw, Vtw);
    attn_kernel<<<dim3(16, 32), 512, 0, stream>>>(QKw, QKw + TSZ, Vtw, Aw);
    gemm_out<<<dim3(8, 64), 256, 0, stream>>>(Aw, Wt + 3 * WSZ, bo, (float*)d_out);
}